// Round 5
// baseline (198.615 us; speedup 1.0000x reference)
//
#include <hip/hip_runtime.h>

#define NB 16
#define C  256
#define H  64
#define W  64
#define E  32
#define F  768
#define HW 4096
#define K5 2048
#define XROWS 4224   // 64 pad + 4096 + 64 pad

typedef __attribute__((ext_vector_type(4))) float f32x4;
typedef __attribute__((ext_vector_type(8))) short s16x8;

__device__ inline unsigned short to_bf16(float f) {
  union { float f; unsigned u; } v; v.f = f;
  unsigned u = v.u;
  u += 0x7fff + ((u >> 16) & 1);
  return (unsigned short)(u >> 16);
}

__device__ inline float from_bf16(unsigned short s) {
  union { unsigned u; float f; } v; v.u = ((unsigned)s) << 16;
  return v.f;
}

__device__ inline void gload16(const void* g, void* l) {
  __builtin_amdgcn_global_load_lds((const __attribute__((address_space(1))) unsigned int*)g,
                                   (__attribute__((address_space(3))) unsigned int*)l, 16, 0, 0);
}

// ---------------------------------------------------------------------------
// Kernel A: fused t1 -> t3 (9x9 dw) -> t4 (5x1 grouped), output bf16.
// Split-e: 2048 blocks (n, 4-ch group, e-half). Each block computes 16 output
// e-rows; t3 staged on 20 rows (t4 halo +-2), t1 on 22 valid rows (conv halo
// +-4). LDS 19.9 KB -> 8 blocks/CU, 8 waves/SIMD (one full residency round).
// t1 reads x straight from global (coalesced, f32); p1 slice staged in LDS f32.
// ---------------------------------------------------------------------------
__global__ __launch_bounds__(256, 8) void k_t4(const float* __restrict__ x,
                                               const float* __restrict__ p1,
                                               const float* __restrict__ p3,
                                               const float* __restrict__ p4,
                                               unsigned short* __restrict__ t4b) {
  const int bx = blockIdx.x;
  const int n  = bx >> 7;
  const int g  = (bx >> 1) & 63;
  const int eh = bx & 1;
  const int c0 = g * 4;
  const int e3_0 = eh * 16;          // first output e-row
  const int rbase = eh ? 0 : 6;      // valid t1 rows occupy [rbase, rbase+22)
  const int ebase = e3_0 - 6 + rbase; // global e of valid row 0 (0 or 10)
  const int tid = threadIdx.x;

  __shared__ __align__(16) float p1s[22][64];             //  5632 B
  __shared__ __align__(16) unsigned short t1s[28][72];    //  4032 B (row r: e=e3_0-6+r; col 4+w)
  __shared__ __align__(16) unsigned short t3s[4][20][64]; // 10240 B (row rt: e3=e3_0-2+rt)

  // zero t1s & t3s once (pads/invalid rows stay zero forever)
  {
    unsigned* u = (unsigned*)&t1s[0][0];
    for (int i = tid; i < 1008; i += 256) u[i] = 0u;
    unsigned* v = (unsigned*)&t3s[0][0][0];
    for (int i = tid; i < 2560; i += 256) v[i] = 0u;
  }
  // stage p1s[ri][h] = p1[h][ebase+ri]  (f32, row = h-contiguous)
  for (int idx = tid; idx < 22 * 64; idx += 256) {
    int ri = idx >> 6, h = idx & 63;
    p1s[ri][h] = p1[h * 32 + ebase + ri];
  }
  __syncthreads();

  for (int q = 0; q < 4; ++q) {
    const int ch = c0 + q;
    const float* xp = x + ((size_t)(n * C + ch)) * HW;
    // ---- t1: rows ri = s+4i (valid only), f32 accum from global x
    {
      const int s = __builtin_amdgcn_readfirstlane(tid >> 6);
      const int w = tid & 63;
      const int nr = (25 - s) >> 2;  // 6,6,5,5 rows per set
      float a[6] = {0.f, 0.f, 0.f, 0.f, 0.f, 0.f};
#pragma unroll
      for (int hb = 0; hb < 4; ++hb) {
        float xv[16];
#pragma unroll
        for (int j = 0; j < 16; ++j) xv[j] = xp[(hb * 16 + j) * 64 + w];
#pragma unroll
        for (int i = 0; i < 6; ++i) {
          if (i < nr) {
            const float* pr = &p1s[s + 4 * i][hb * 16];
#pragma unroll
            for (int jb = 0; jb < 4; ++jb) {
              float4 wv = *(const float4*)(pr + jb * 4);
              a[i] += xv[jb * 4 + 0] * wv.x + xv[jb * 4 + 1] * wv.y +
                      xv[jb * 4 + 2] * wv.z + xv[jb * 4 + 3] * wv.w;
            }
          }
        }
      }
#pragma unroll
      for (int i = 0; i < 6; ++i)
        if (i < nr) t1s[rbase + s + 4 * i][4 + w] = to_bf16(a[i]);
    }
    __syncthreads();
    // ---- t3: 9x9 depthwise on 20 rows (threads 0..159), 16-wide window
    {
      const int rt = tid >> 3;
      const int wq = tid & 7;
      const int e3 = e3_0 - 2 + rt;
      if (rt < 20 && e3 >= 0 && e3 < 32) {
        const float* w3 = p3 + ch * 81;
        float o[8];
#pragma unroll
        for (int k = 0; k < 8; ++k) o[k] = 0.f;
#pragma unroll
        for (int i = 0; i < 9; ++i) {
          const char* base = (const char*)t1s + 144 * (rt + i) + 16 * wq;
          uint4 wv0 = *(const uint4*)base;
          uint4 wv1 = *(const uint4*)(base + 16);
          const unsigned short* ws0 = (const unsigned short*)&wv0;
          const unsigned short* ws1 = (const unsigned short*)&wv1;
          float win[16];
#pragma unroll
          for (int k = 0; k < 8; ++k) { win[k] = from_bf16(ws0[k]); win[8 + k] = from_bf16(ws1[k]); }
#pragma unroll
          for (int j = 0; j < 9; ++j) {
            float wt = w3[i * 9 + j];
#pragma unroll
            for (int k = 0; k < 8; ++k) o[k] += win[j + k] * wt;
          }
        }
        unsigned short ob[8];
#pragma unroll
        for (int k = 0; k < 8; ++k) ob[k] = to_bf16(o[k]);
        *(uint4*)&t3s[q][rt][wq * 8] = *(const uint4*)ob;
      }
    }
    __syncthreads();
  }
  // ---- t4: (5,1) grouped conv; thread = (rt4, 4 w), 4 output channels
  {
    const int rt4 = tid >> 4;          // 0..15 -> output e = e3_0 + rt4
    const int w4 = (tid & 15) * 4;
    float acc[4][4];
#pragma unroll
    for (int qo = 0; qo < 4; ++qo)
#pragma unroll
      for (int k = 0; k < 4; ++k) acc[qo][k] = 0.f;
#pragma unroll
    for (int ci = 0; ci < 4; ++ci) {
#pragma unroll
      for (int u = 0; u < 5; ++u) {
        uint2 v = *(const uint2*)&t3s[ci][rt4 + u][w4];
        const unsigned short* vs = (const unsigned short*)&v;
        float vf[4];
#pragma unroll
        for (int k = 0; k < 4; ++k) vf[k] = from_bf16(vs[k]);
#pragma unroll
        for (int qo = 0; qo < 4; ++qo) {
          float wv = p4[(c0 + qo) * 20 + ci * 5 + u];
#pragma unroll
          for (int k = 0; k < 4; ++k) acc[qo][k] += vf[k] * wv;
        }
      }
    }
#pragma unroll
    for (int qo = 0; qo < 4; ++qo) {
      unsigned short ob[4];
#pragma unroll
      for (int k = 0; k < 4; ++k) ob[k] = to_bf16(acc[qo][k]);
      *(uint2*)(t4b + ((size_t)(n * C + c0 + qo)) * (E * W) + (e3_0 + rt4) * 64 + w4) =
          *(const uint2*)ob;
    }
  }
}

// ---------------------------------------------------------------------------
// p5 [2048][768] f32 -> p5t [768][2048] bf16 (transpose + convert)
// ---------------------------------------------------------------------------
__global__ __launch_bounds__(256) void k_p5t(const float* __restrict__ p5,
                                             unsigned short* __restrict__ p5t) {
  const int f0 = blockIdx.x * 64;
  const int k0 = blockIdx.y * 64;
  const int tid = threadIdx.x;
  __shared__ __align__(16) unsigned short ls[64][264];
  int fl = tid & 63, k4 = tid >> 6;
  for (int i = 0; i < 16; ++i) {
    int kl = k4 * 16 + i;
    ls[fl][kl] = to_bf16(p5[(size_t)(k0 + kl) * F + f0 + fl]);
  }
  __syncthreads();
#pragma unroll
  for (int j = 0; j < 2; ++j) {
    int chunk = tid + 256 * j;
    int row = chunk >> 3, slot = chunk & 7;
    *(uint4*)(p5t + (size_t)(f0 + row) * K5 + k0 + slot * 8) = *(const uint4*)&ls[row][slot * 8];
  }
}

// ---------------------------------------------------------------------------
// x [n][c][h][w] f32 -> xt [n][64 + h*64+w + 64][c] bf16, zero pads
// ---------------------------------------------------------------------------
__global__ __launch_bounds__(256) void k_xt(const float* __restrict__ x,
                                            unsigned short* __restrict__ xt) {
  const int hi = blockIdx.x;   // 0..65
  const int n = blockIdx.y;
  const int tid = threadIdx.x;
  unsigned short* dst = xt + ((size_t)n * XROWS + hi * 64) * C;
  if (hi == 0 || hi == 65) {
    uint4 z = make_uint4(0, 0, 0, 0);
    uint4* d4 = (uint4*)dst;
#pragma unroll
    for (int i = 0; i < 8; ++i) d4[tid + 256 * i] = z;
    return;
  }
  const int h = hi - 1;
  __shared__ __align__(16) unsigned short ls[64][264];
  const float* xp = x + ((size_t)n * C) * HW + h * 64;
  int w = tid & 63, c4 = tid >> 6;
  for (int i = 0; i < 64; ++i) {
    int c = c4 * 64 + i;
    ls[w][c] = to_bf16(xp[(size_t)c * HW + w]);
  }
  __syncthreads();
#pragma unroll
  for (int j = 0; j < 8; ++j) {
    int chunk = tid + 256 * j;          // 2048 chunks of 16B
    int row = chunk >> 5, slot = chunk & 31;
    *(uint4*)(dst + row * C + slot * 8) = *(const uint4*)&ls[row][slot * 8];
  }
}

// ---------------------------------------------------------------------------
// k_t5m: t5[4096][768] f32 = t4b[4096][2048]bf16 x p5t^T.  64x64 tile ->
// 768 blocks (3/CU) for TLP; 4 waves as 2x2, wave-tile 32x32.
// ---------------------------------------------------------------------------
__global__ __launch_bounds__(256) void k_t5m(const unsigned short* __restrict__ A,
                                             const unsigned short* __restrict__ Bt,
                                             float* __restrict__ Cout) {
  const int n0 = blockIdx.x * 64;   // 12
  const int m0 = blockIdx.y * 64;   // 64
  const int tid = threadIdx.x;
  const int lane = tid & 63;
  const int wave = tid >> 6;
  const int wm = wave >> 1, wn = wave & 1;
  __shared__ __align__(16) short As[4096];
  __shared__ __align__(16) short Bs[4096];
  f32x4 acc[2][2] = {};
  const int lr = lane >> 3;
  const int ls = lane & 7;

  for (int k0 = 0; k0 < K5; k0 += 64) {
#pragma unroll
    for (int i = 0; i < 2; ++i) {
      int inst = wave * 2 + i;       // 0..7
      int r = inst * 8 + lr;         // 0..63
      int sw = ls ^ (r & 7);
      gload16((const char*)(A + (size_t)(m0 + r) * K5 + k0) + sw * 16,
              (char*)As + inst * 1024);
      gload16((const char*)(Bt + (size_t)(n0 + r) * K5 + k0) + sw * 16,
              (char*)Bs + inst * 1024);
    }
    __syncthreads();
#pragma unroll
    for (int kh = 0; kh < 2; ++kh) {
      s16x8 af[2], bf[2];
#pragma unroll
      for (int mi = 0; mi < 2; ++mi) {
        int row = wm * 32 + mi * 16 + (lane & 15);
        int byte = (row * 128 + kh * 64 + (lane >> 4) * 16) ^ ((row & 7) << 4);
        af[mi] = *(const s16x8*)((const char*)As + byte);
      }
#pragma unroll
      for (int ni = 0; ni < 2; ++ni) {
        int row = wn * 32 + ni * 16 + (lane & 15);
        int byte = (row * 128 + kh * 64 + (lane >> 4) * 16) ^ ((row & 7) << 4);
        bf[ni] = *(const s16x8*)((const char*)Bs + byte);
      }
#pragma unroll
      for (int mi = 0; mi < 2; ++mi)
#pragma unroll
        for (int ni = 0; ni < 2; ++ni)
          acc[mi][ni] = __builtin_amdgcn_mfma_f32_16x16x32_bf16(af[mi], bf[ni], acc[mi][ni], 0, 0, 0);
    }
    __syncthreads();
  }
#pragma unroll
  for (int mi = 0; mi < 2; ++mi) {
    int rbase = m0 + wm * 32 + mi * 16 + (lane >> 4) * 4;
#pragma unroll
    for (int ni = 0; ni < 2; ++ni) {
      int col = n0 + wn * 32 + ni * 16 + (lane & 15);
#pragma unroll
      for (int q = 0; q < 4; ++q)
        Cout[(size_t)(rbase + q) * F + col] = acc[mi][ni][q];
    }
  }
}

// ---------------------------------------------------------------------------
// k_t6: t5 f32 -> 3-tap dw conv (original f order) -> scale -> bf16 in f' order
// f' = kk*256 + c2  (f = 3*c2 + kk)
// ---------------------------------------------------------------------------
__global__ __launch_bounds__(256) void k_t6(const float* __restrict__ t5,
                                            const float* __restrict__ p6,
                                            unsigned short* __restrict__ t6b) {
  int idx = blockIdx.x * 256 + threadIdx.x;
  if (idx >= NB * C * F) return;
  int fp = idx % F;
  int nc = idx / F;
  int c = nc & 255;
  int c2 = fp & 255;
  int kk = fp >> 8;
  int f = 3 * c2 + kk;
  const float* row = t5 + (size_t)nc * F;
  const float* wt = p6 + c * 3;
  float acc = row[f] * wt[1];
  if (f > 0) acc += row[f - 1] * wt[0];
  if (f < F - 1) acc += row[f + 1] * wt[2];
  t6b[idx] = to_bf16(acc * 0.03608439182435161f);
}

// ---------------------------------------------------------------------------
// k_outm: out[n][256][4096] f32 = t6b[n][256][768] x B' (from xt, shifted rows)
// ---------------------------------------------------------------------------
__global__ __launch_bounds__(256) void k_outm(const unsigned short* __restrict__ t6b,
                                              const unsigned short* __restrict__ xt,
                                              float* __restrict__ outp) {
  const int p0 = blockIdx.x * 128;   // 32
  const int m0 = blockIdx.y * 128;   // 2
  const int n  = blockIdx.z;         // 16
  const int tid = threadIdx.x;
  const int lane = tid & 63;
  const int wave = tid >> 6;
  const int wm = wave >> 1, wn = wave & 1;
  __shared__ __align__(16) short As[8192];
  __shared__ __align__(16) short Bs[8192];
  f32x4 acc[4][4] = {};
  const int lr = lane >> 3;
  const int ls = lane & 7;
  const unsigned short* Abase = t6b + (size_t)(n * C) * F;
  const unsigned short* Xbase = xt + (size_t)n * XROWS * C;

  for (int kt = 0; kt < 12; ++kt) {
    int k0 = kt * 64;
    int kk = k0 >> 8;
    int c20 = k0 & 255;
#pragma unroll
    for (int i = 0; i < 4; ++i) {
      int inst = wave * 4 + i;
      int r = inst * 8 + lr;
      int sw = ls ^ (r & 7);
      gload16((const char*)(Abase + (size_t)(m0 + r) * F + k0) + sw * 16,
              (char*)As + inst * 1024);
      gload16((const char*)(Xbase + (size_t)(p0 + r + (kk << 6)) * C + c20) + sw * 16,
              (char*)Bs + inst * 1024);
    }
    __syncthreads();
#pragma unroll
    for (int kh = 0; kh < 2; ++kh) {
      s16x8 af[4], bf[4];
#pragma unroll
      for (int mi = 0; mi < 4; ++mi) {
        int row = wm * 64 + mi * 16 + (lane & 15);
        int byte = (row * 128 + kh * 64 + (lane >> 4) * 16) ^ ((row & 7) << 4);
        af[mi] = *(const s16x8*)((const char*)As + byte);
      }
#pragma unroll
      for (int ni = 0; ni < 4; ++ni) {
        int row = wn * 64 + ni * 16 + (lane & 15);
        int byte = (row * 128 + kh * 64 + (lane >> 4) * 16) ^ ((row & 7) << 4);
        bf[ni] = *(const s16x8*)((const char*)Bs + byte);
      }
#pragma unroll
      for (int mi = 0; mi < 4; ++mi)
#pragma unroll
        for (int ni = 0; ni < 4; ++ni)
          acc[mi][ni] = __builtin_amdgcn_mfma_f32_16x16x32_bf16(af[mi], bf[ni], acc[mi][ni], 0, 0, 0);
    }
    __syncthreads();
  }
  float* obase = outp + (size_t)(n * C) * HW;
#pragma unroll
  for (int mi = 0; mi < 4; ++mi) {
    int rbase = m0 + wm * 64 + mi * 16 + (lane >> 4) * 4;
#pragma unroll
    for (int ni = 0; ni < 4; ++ni) {
      int col = p0 + wn * 64 + ni * 16 + (lane & 15);
#pragma unroll
      for (int q = 0; q < 4; ++q)
        obase[(size_t)(rbase + q) * HW + col] = acc[mi][ni][q];
    }
  }
}

extern "C" void kernel_launch(void* const* d_in, const int* in_sizes, int n_in,
                              void* d_out, int out_size, void* d_ws, size_t ws_size,
                              hipStream_t stream) {
  (void)in_sizes; (void)n_in; (void)out_size; (void)ws_size;
  const float* x  = (const float*)d_in[0];
  const float* p1 = (const float*)d_in[1];
  const float* p3 = (const float*)d_in[2];
  const float* p4 = (const float*)d_in[3];
  const float* p5 = (const float*)d_in[4];
  const float* p6 = (const float*)d_in[5];
  float* out = (float*)d_out;

  char* ws = (char*)d_ws;
  // region [0, 34.6MB): early = {t4b, p5t, t5}; late (after k_t6) = xt
  unsigned short* t4b = (unsigned short*)ws;                          // 16.8 MB
  unsigned short* p5t = (unsigned short*)(ws + 16777216);             //  3.1 MB
  float*          t5  = (float*)(ws + 19922944);                      // 12.6 MB
  unsigned short* xt  = (unsigned short*)ws;                          // 34.6 MB (overlays t4b/p5t/t5)
  unsigned short* t6b = (unsigned short*)(ws + 34603008);             //  6.3 MB

  k_t4 <<<dim3(NB * 64 * 2), 256, 0, stream>>>(x, p1, p3, p4, t4b);
  k_p5t<<<dim3(12, 32), 256, 0, stream>>>(p5, p5t);
  k_t5m<<<dim3(12, 64), 256, 0, stream>>>(t4b, p5t, t5);
  k_t6 <<<dim3((NB * C * F + 255) / 256), 256, 0, stream>>>(t5, p6, t6b);
  k_xt <<<dim3(66, NB), 256, 0, stream>>>(x, xt);
  k_outm<<<dim3(32, 2, NB), 256, 0, stream>>>(t6b, xt, out);
}